// Round 12
// baseline (272.232 us; speedup 1.0000x reference)
//
#include <hip/hip_runtime.h>
#include <hip/hip_fp16.h>

// gap_2370821948148 — circle-loss scalar reduction. B=4096, K=64, N=65.
// Round 12: SPILL FIX. r11's WRITE_SIZE=47MB + FETCH+17MB + VGPR_Count=32
// proved hc[32] was spilled to scratch under launch_bounds(128,8) (the
// "register" hinge cache became a global-memory round trip, ~134MB traffic).
// This round removes hc[] entirely: two-pass structure with only a 2-VGPR
// negm bitmask; pass 2 re-reads values (wave0: LDS u16, L0-hot; wave1:
// global f32, L1/L2-hot). Honest ~30 VGPR -> true 8 waves/SIMD residency.
// Kept from r10/r11: wave0 solo-stages the f16 tile (NO barrier — wave1
// never touches LDS), wave1 reads coalesced f32 columns from global and
// pos-points via wave-uniform s_loads.
//   CONFIRMED: f32 inputs; bf16 scalar out (4-byte dual-encode, exact under
//   u16 readback); mask width runtime-detected. DO-NOT-USE: last-block
//   finalize (r3/r4 failed silently); minwaves that forces VGPR < live set.

#define R2_POS 0.36f     // 0.6^2
#define R2_NEG 1.44f     // (2*0.6)^2
#define GAMMA_C 0.5f
#define NBATCH 4096
#define NPART (NBATCH * 2)

__device__ __forceinline__ int maskbit(const void* p, int i, int mode) {
    if (mode == 0) return ((const unsigned*)p)[i] != 0u;          // 4B elems
    if (mode == 1) return ((const unsigned short*)p)[i] != 0;     // 2B elems
    return ((const unsigned char*)p)[i] != 0;                     // u8/bool
}

__global__ __launch_bounds__(128, 8)
void fused_kernel(const float* __restrict__ posp,
                  const float* __restrict__ ancp,
                  const void* __restrict__ pmp,
                  const void* __restrict__ amp,
                  const float* __restrict__ msp,
                  const float* __restrict__ xfp,
                  float* __restrict__ partials) {
    __shared__ __half2 tile2[2113];      // halfwords 0..4225 (+ofs trick)
    __shared__ float4 ancs[64];          // transformed anchors (wave0 only)

    const int tid = threadIdx.x;
    const int b = blockIdx.x;            // batch
    const int w = tid >> 6;              // 0 = rows (loss1), 1 = cols (loss2)
    const int l = tid & 63;              // lane
    const int ofs = b & 1;               // halfword shift for odd batches

    // ---- mask element-width detection (uniform, cached) ----
    unsigned mw0 = ((const unsigned*)pmp)[l];
    bool okw = (mw0 == 0u) || (mw0 == 1u) || (mw0 == 0x3F800000u);
    unsigned hh0 = mw0 & 0xFFFFu, hh1 = mw0 >> 16;
    bool okh = (hh0 == 0u || hh0 == 0x3F80u) && (hh1 == 0u || hh1 == 0x3F80u);
    int mmode = (__ballot(okw) == ~0ULL) ? 0 : ((__ballot(okh) == ~0ULL) ? 1 : 2);

    // ---- transform (uniform addresses -> s_load, lives in SGPRs) ----
    float T[12];
#pragma unroll
    for (int e = 0; e < 3; ++e)
#pragma unroll
        for (int d = 0; d < 4; ++d) T[e * 4 + d] = xfp[e * 4 + d];

    // ---- own points: lane l = point l of batch b ----
    const int pb = (b * 64 + l) * 3;
    const float px = posp[pb], py = posp[pb + 1], pz = posp[pb + 2];
    const float r0 = ancp[pb], r1 = ancp[pb + 1], r2 = ancp[pb + 2];
    const float ax = T[0] * r0 + T[1] * r1 + T[2]  * r2 + T[3];
    const float ay = T[4] * r0 + T[5] * r1 + T[6]  * r2 + T[7];
    const float az = T[8] * r0 + T[9] * r1 + T[10] * r2 + T[11];

    // ---- masks -> per-wave ballots (SGPR pairs) ----
    const int mi = b * 64 + l;
    const unsigned long long pmM = __ballot(maskbit(pmp, mi, mmode) != 0);
    const unsigned long long amM = __ballot(maskbit(amp, mi, mmode) != 0);

    float psum = 0.f; int pcnt = 0; float slack;
    unsigned nlo = 0u, nhi = 0u;         // neg bitmask — 2 VGPRs, no hc[]
    float hv = 0.f;

    if (w == 0) {
        // ---- SOLO staging (no barrier: only wave0 reads tile2/ancs;
        // wave-internal ds ordering is lgkmcnt-guaranteed) ----
        ancs[l] = make_float4(ax, ay, az, 0.f);
        const float2* src = (const float2*)(msp + (size_t)b * 4225 - ofs);
#pragma unroll
        for (int k = 0; k < 17; ++k) {
            int p = l + 64 * k;                        // pair index
            if (p < 1056) {
                float2 a = src[2 * p], c = src[2 * p + 1];
                tile2[2 * p]     = __float22half2_rn(a);
                tile2[2 * p + 1] = __float22half2_rn(c);
            } else if (p == 1056) {
                tile2[2112] = __float22half2_rn(src[2112]);
            }
        }

        // ===== loss1 pass 1: stats only (psum/pcnt/negm) =====
        const __half* row = ((const __half*)tile2) + ofs + l * 65;
        const bool pmL = (pmM >> l) & 1ULL;
#pragma unroll
        for (int j = 0; j < 64; ++j) {
            float v = __half2float(row[j]);
            float4 a = ancs[j];                        // b128 broadcast
            float dx = px - a.x, dy = py - a.y, dz = pz - a.z;
            float d2 = dx * dx + dy * dy + dz * dz;
            bool pos = pmL && ((amM >> j) & 1ULL) && (d2 < R2_POS);
            psum -= pos ? v : 0.f;
            pcnt += pos ? 1 : 0;
            bool neg = d2 > R2_NEG;                    // gt_neg UNMASKED
            if (j < 32) nlo |= neg ? (1u << j) : 0u;
            else        nhi |= neg ? (1u << (j - 32)) : 0u;
        }
        slack = __half2float(row[64]);
        const float ps = pcnt ? psum / (float)pcnt : -slack;
        const float c = ps + GAMMA_C;
        // ===== pass 2: hinge, re-reading L0-hot LDS =====
#pragma unroll
        for (int j = 0; j < 32; ++j)
            if ((nlo >> j) & 1u)
                hv += fmaxf(c + __half2float(row[j]), 0.f);
#pragma unroll
        for (int j = 32; j < 64; ++j)
            if ((nhi >> (j - 32)) & 1u)
                hv += fmaxf(c + __half2float(row[j]), 0.f);
        if (pcnt) hv += fmaxf(c + slack, 0.f);
        hv += 1.f;
    } else {
        // ===== loss2 pass 1: coalesced global f32 columns + uniform points =
        const float* mcol = msp + (size_t)b * 4225 + l;
        const bool amL = (amM >> l) & 1ULL;
#pragma unroll
        for (int r = 0; r < 64; ++r) {
            float v = mcol[r * 65];
            const int qb = (b * 64 + r) * 3;           // uniform -> s_load
            float qx = posp[qb], qy = posp[qb + 1], qz = posp[qb + 2];
            float dx = qx - ax, dy = qy - ay, dz = qz - az;
            float d2 = dx * dx + dy * dy + dz * dz;
            bool pos = ((pmM >> r) & 1ULL) && amL && (d2 < R2_POS);
            psum -= pos ? v : 0.f;
            pcnt += pos ? 1 : 0;
            bool neg = d2 > R2_NEG;
            if (r < 32) nlo |= neg ? (1u << r) : 0u;
            else        nhi |= neg ? (1u << (r - 32)) : 0u;
        }
        slack = mcol[64 * 65];
        const float ps = pcnt ? psum / (float)pcnt : -slack;
        const float c = ps + GAMMA_C;
        // ===== pass 2: hinge, re-reading L1/L2-hot global =====
#pragma unroll
        for (int r = 0; r < 32; ++r)
            if ((nlo >> r) & 1u)
                hv += fmaxf(c + mcol[r * 65], 0.f);
#pragma unroll
        for (int r = 32; r < 64; ++r)
            if ((nhi >> (r - 32)) & 1u)
                hv += fmaxf(c + mcol[r * 65], 0.f);
        if (pcnt) hv += fmaxf(c + slack, 0.f);
        hv += 1.f;
    }

    float result = __logf(hv);

    // ---- one butterfly per wave, lane0 stores partial ----
#pragma unroll
    for (int off = 1; off < 64; off <<= 1)
        result += __shfl_xor(result, off, 64);
    if (l == 0) partials[b * 2 + w] = result;          // plain store, no init
}

// Separate unconditional finalize (proven). 4-byte dual-encoded write:
// low u16 = exact bf16 bits; as f32 also decodes to ~value(h).
__global__ void finalize_kernel(const float* __restrict__ partials,
                                unsigned* __restrict__ out) {
    __shared__ float red[4];
    const int tid = threadIdx.x;
    float s = 0.f;
    for (int i = tid; i < NPART; i += 256) s += partials[i];
#pragma unroll
    for (int off = 1; off < 64; off <<= 1) s += __shfl_xor(s, off, 64);
    if ((tid & 63) == 0) red[tid >> 6] = s;
    __syncthreads();
    if (tid == 0) {
        float tot = red[0] + red[1] + red[2] + red[3];
        float loss = tot * (1.0f / (2.0f * NBATCH * 64.0f));
        unsigned bits = __float_as_uint(loss);
        unsigned h = (bits + 0x7FFFu + ((bits >> 16) & 1u)) >> 16;  // rne bf16
        out[0] = (h << 16) | h;
    }
}

extern "C" void kernel_launch(void* const* d_in, const int* in_sizes, int n_in,
                              void* d_out, int out_size, void* d_ws, size_t ws_size,
                              hipStream_t stream) {
    (void)in_sizes; (void)n_in; (void)out_size; (void)ws_size;
    const float* posp = (const float*)d_in[0];
    const float* ancp = (const float*)d_in[1];
    const void* pmp = d_in[2];
    const void* amp = d_in[3];
    const float* msp = (const float*)d_in[4];
    const float* xfp = (const float*)d_in[5];

    // ws[0..NPART): per-wave partials, fully overwritten every call.
    fused_kernel<<<NBATCH, 128, 0, stream>>>(posp, ancp, pmp, amp, msp, xfp,
                                             (float*)d_ws);
    finalize_kernel<<<1, 256, 0, stream>>>((const float*)d_ws,
                                           (unsigned*)d_out);
}

// Round 13
// 137.369 us; speedup vs baseline: 1.9818x; 1.9818x over previous
//
#include <hip/hip_runtime.h>
#include <hip/hip_fp16.h>

// gap_2370821948148 — circle-loss scalar reduction. B=4096, K=64, N=65.
// Round 13: reproduce r10 (best: 138.3us total) minus its slack.
//   POST-MORTEM LEDGER:
//   - r12: two-pass global re-read => compiler CSE'd 64 loads across the ps
//     barrier => 64 live f32 => scratch spill (FETCH 270MB/WRITE 259MB).
//   - r11: minwaves=8 (64-VGPR budget) + hc[32] => spill (WRITE 47MB).
//   - r10: hc[32] f16 under (128,7)=73-VGPR budget => fit, fused ~38-41us.
//   RULES: candidates live in packed-f16 regs (32 VGPR); never force
//   minwaves>=8 with hc live; never re-read global across ps.
//   This round = r10 + (a) wave0 solo-stages, barrier deleted (wave1 is
//   LDS-free; sound r11 change, spill was the real regression) + (b) T[]
//   pinned to SGPRs via one-time readfirstlane (protects the 73-reg fit).
//   CONFIRMED: f32 inputs; bf16 scalar out (4-byte dual-encode, exact under
//   u16 readback); mask width runtime-detected. DO-NOT-USE: last-block
//   finalize (r3/r4 failed silently).

#define R2_POS 0.36f     // 0.6^2
#define R2_NEG 1.44f     // (2*0.6)^2
#define GAMMA_C 0.5f
#define NBATCH 4096
#define NPART (NBATCH * 2)
#define HCNEG -1024.0f   // hinge filler: ps+gamma+HCNEG << 0 in f16 range

typedef _Float16 hf2 __attribute__((ext_vector_type(2)));

__device__ __forceinline__ int maskbit(const void* p, int i, int mode) {
    if (mode == 0) return ((const unsigned*)p)[i] != 0u;          // 4B elems
    if (mode == 1) return ((const unsigned short*)p)[i] != 0;     // 2B elems
    return ((const unsigned char*)p)[i] != 0;                     // u8/bool
}

__device__ __forceinline__ float sload(float v) {   // pin uniform to SGPR
    return __uint_as_float(__builtin_amdgcn_readfirstlane(__float_as_uint(v)));
}

__global__ __launch_bounds__(128, 7)
void fused_kernel(const float* __restrict__ posp,
                  const float* __restrict__ ancp,
                  const void* __restrict__ pmp,
                  const void* __restrict__ amp,
                  const float* __restrict__ msp,
                  const float* __restrict__ xfp,
                  float* __restrict__ partials) {
    __shared__ __half2 tile2[2113];      // halfwords 0..4225 (+ofs trick)
    __shared__ float4 ancs[64];          // transformed anchors (wave0 only)

    const int tid = threadIdx.x;
    const int b = blockIdx.x;            // batch
    const int w = tid >> 6;              // 0 = rows (loss1), 1 = cols (loss2)
    const int l = tid & 63;              // lane
    const int ofs = b & 1;               // halfword shift for odd batches

    // ---- mask element-width detection (uniform, cached) ----
    unsigned mw0 = ((const unsigned*)pmp)[l];
    bool okw = (mw0 == 0u) || (mw0 == 1u) || (mw0 == 0x3F800000u);
    unsigned hh0 = mw0 & 0xFFFFu, hh1 = mw0 >> 16;
    bool okh = (hh0 == 0u || hh0 == 0x3F80u) && (hh1 == 0u || hh1 == 0x3F80u);
    int mmode = (__ballot(okw) == ~0ULL) ? 0 : ((__ballot(okh) == ~0ULL) ? 1 : 2);

    // ---- transform, pinned to SGPRs ----
    float T[12];
#pragma unroll
    for (int e = 0; e < 3; ++e)
#pragma unroll
        for (int d = 0; d < 4; ++d) T[e * 4 + d] = sload(xfp[e * 4 + d]);

    // ---- own points: lane l = point l of batch b ----
    const int pb = (b * 64 + l) * 3;
    const float px = posp[pb], py = posp[pb + 1], pz = posp[pb + 2];
    const float r0 = ancp[pb], r1 = ancp[pb + 1], r2 = ancp[pb + 2];
    const float ax = T[0] * r0 + T[1] * r1 + T[2]  * r2 + T[3];
    const float ay = T[4] * r0 + T[5] * r1 + T[6]  * r2 + T[7];
    const float az = T[8] * r0 + T[9] * r1 + T[10] * r2 + T[11];

    // ---- masks -> per-wave ballots (SGPR pairs) ----
    const int mi = b * 64 + l;
    const unsigned long long pmM = __ballot(maskbit(pmp, mi, mmode) != 0);
    const unsigned long long amM = __ballot(maskbit(amp, mi, mmode) != 0);

    float psum = 0.f; int pcnt = 0; float slack;
    hf2 hc[32];                          // packed hinge candidates (32 VGPR)

    if (w == 0) {
        // ---- SOLO staging (no barrier: only wave0 reads tile2/ancs;
        // wave-internal ds_write->ds_read ordering is lgkmcnt-guaranteed) ---
        ancs[l] = make_float4(ax, ay, az, 0.f);
        const float2* src = (const float2*)(msp + (size_t)b * 4225 - ofs);
#pragma unroll
        for (int k = 0; k < 17; ++k) {
            int p = l + 64 * k;                        // pair index
            if (p < 1056) {
                float2 a = src[2 * p], c = src[2 * p + 1];
                tile2[2 * p]     = __float22half2_rn(a);
                tile2[2 * p + 1] = __float22half2_rn(c);
            } else if (p == 1056) {
                tile2[2112] = __float22half2_rn(src[2112]);
            }
        }

        // ===== loss1: lane l = row l; f16 LDS values + float4 anc bcast ====
        const __half* row = ((const __half*)tile2) + ofs + l * 65;
        const bool pmL = (pmM >> l) & 1ULL;
#pragma unroll
        for (int jj = 0; jj < 32; ++jj) {
            float h0, h1;
#pragma unroll
            for (int s = 0; s < 2; ++s) {
                const int j = 2 * jj + s;
                float v = __half2float(row[j]);
                float4 a = ancs[j];                    // one b128 broadcast
                float dx = px - a.x, dy = py - a.y, dz = pz - a.z;
                float d2 = dx * dx + dy * dy + dz * dz;
                bool pos = pmL && ((amM >> j) & 1ULL) && (d2 < R2_POS);
                psum -= pos ? v : 0.f;
                pcnt += pos ? 1 : 0;
                float hcv = (d2 > R2_NEG) ? v : HCNEG; // gt_neg UNMASKED
                if (s == 0) h0 = hcv; else h1 = hcv;
            }
            hf2 h; h[0] = (_Float16)h0; h[1] = (_Float16)h1;
            hc[jj] = h;
        }
        slack = __half2float(row[64]);
    } else {
        // ===== loss2: lane l = col l; coalesced global f32 values (L2-hot
        // from wave0's staging fetch) + wave-uniform point loads ============
        const float* mcol = msp + (size_t)b * 4225 + l;
        const bool amL = (amM >> l) & 1ULL;
#pragma unroll
        for (int jj = 0; jj < 32; ++jj) {
            float h0, h1;
#pragma unroll
            for (int s = 0; s < 2; ++s) {
                const int r = 2 * jj + s;
                float v = mcol[r * 65];
                const int qb = (b * 64 + r) * 3;       // uniform -> s_load
                float qx = posp[qb], qy = posp[qb + 1], qz = posp[qb + 2];
                float dx = qx - ax, dy = qy - ay, dz = qz - az;
                float d2 = dx * dx + dy * dy + dz * dz;
                bool pos = ((pmM >> r) & 1ULL) && amL && (d2 < R2_POS);
                psum -= pos ? v : 0.f;
                pcnt += pos ? 1 : 0;
                float hcv = (d2 > R2_NEG) ? v : HCNEG;
                if (s == 0) h0 = hcv; else h1 = hcv;
            }
            hf2 h; h[0] = (_Float16)h0; h[1] = (_Float16)h1;
            hc[jj] = h;
        }
        slack = mcol[64 * 65];
    }

    const float ps = pcnt ? psum / (float)pcnt : -slack;

    // ---- packed branch-free hinge: max(hc + (ps+gamma), 0), f32 accum ----
    const _Float16 ch = (_Float16)(ps + GAMMA_C);
    const hf2 C2 = {ch, ch};
    const hf2 Z = {(_Float16)0.f, (_Float16)0.f};
    float hv = 0.f;
#pragma unroll
    for (int k = 0; k < 32; ++k) {
        hf2 x = hc[k] + C2;                  // v_pk_add_f16
        x = __builtin_elementwise_max(x, Z); // v_pk_max_f16
        hv += (float)x[0] + (float)x[1];
    }
    if (pcnt) hv += fmaxf(ps + slack + GAMMA_C, 0.f);
    float result = __logf(hv + 1.f);

    // ---- one butterfly per wave, lane0 stores partial ----
#pragma unroll
    for (int off = 1; off < 64; off <<= 1)
        result += __shfl_xor(result, off, 64);
    if (l == 0) partials[b * 2 + w] = result;          // plain store, no init
}

// Separate unconditional finalize (proven). 4-byte dual-encoded write:
// low u16 = exact bf16 bits; as f32 also decodes to ~value(h).
__global__ void finalize_kernel(const float* __restrict__ partials,
                                unsigned* __restrict__ out) {
    __shared__ float red[4];
    const int tid = threadIdx.x;
    float s = 0.f;
    for (int i = tid; i < NPART; i += 256) s += partials[i];
#pragma unroll
    for (int off = 1; off < 64; off <<= 1) s += __shfl_xor(s, off, 64);
    if ((tid & 63) == 0) red[tid >> 6] = s;
    __syncthreads();
    if (tid == 0) {
        float tot = red[0] + red[1] + red[2] + red[3];
        float loss = tot * (1.0f / (2.0f * NBATCH * 64.0f));
        unsigned bits = __float_as_uint(loss);
        unsigned h = (bits + 0x7FFFu + ((bits >> 16) & 1u)) >> 16;  // rne bf16
        out[0] = (h << 16) | h;
    }
}

extern "C" void kernel_launch(void* const* d_in, const int* in_sizes, int n_in,
                              void* d_out, int out_size, void* d_ws, size_t ws_size,
                              hipStream_t stream) {
    (void)in_sizes; (void)n_in; (void)out_size; (void)ws_size;
    const float* posp = (const float*)d_in[0];
    const float* ancp = (const float*)d_in[1];
    const void* pmp = d_in[2];
    const void* amp = d_in[3];
    const float* msp = (const float*)d_in[4];
    const float* xfp = (const float*)d_in[5];

    // ws[0..NPART): per-wave partials, fully overwritten every call.
    fused_kernel<<<NBATCH, 128, 0, stream>>>(posp, ancp, pmp, amp, msp, xfp,
                                             (float*)d_ws);
    finalize_kernel<<<1, 256, 0, stream>>>((const float*)d_ws,
                                           (unsigned*)d_out);
}